// Round 1
// baseline (103.277 us; speedup 1.0000x reference)
//
#include <hip/hip_runtime.h>
#include <stdint.h>

#define NB 128
#define G 32
#define G2 1024
#define NC 80
#define ST 90            // 80 logits + 2*5 bbox
#define IMGW 448.0f
#define NCELL (NB * G2)

// ---------------------------------------------------------------------------
// Kernel 1: per-cell decode. One thread per grid cell.
//  - copies the 80 class logits to out0 and computes argmax label
//  - selects best of the 2 bboxes by confidence -> out1
//  - decodes to pixel box, clips -> out2; score -> out3; reserve -> out4
//  - stashes {clipped box, score, label} in workspace for the NMS kernel
// ---------------------------------------------------------------------------
__global__ __launch_bounds__(256) void percell_kernel(
    const float* __restrict__ x,
    float* __restrict__ out0, float* __restrict__ out1,
    float* __restrict__ out2, float* __restrict__ out3,
    float* __restrict__ out4,
    float4* __restrict__ ws_boxes, float* __restrict__ ws_score,
    int* __restrict__ ws_label)
{
#pragma clang fp contract(off)
    int cell = blockIdx.x * blockDim.x + threadIdx.x;
    if (cell >= NCELL) return;
    // x + cell*90 floats = cell*360 bytes -> 8B aligned, use float2 loads
    const float2* p2 = (const float2*)(x + (size_t)cell * ST);

    float bv = -INFINITY;
    int lab = 0;
    float* o0 = out0 + (size_t)cell * NC;   // 320B per cell -> 16B aligned
#pragma unroll
    for (int c = 0; c < NC; c += 4) {
        float2 a = p2[c >> 1];
        float2 b = p2[(c >> 1) + 1];
        if (a.x > bv) { bv = a.x; lab = c; }
        if (a.y > bv) { bv = a.y; lab = c + 1; }
        if (b.x > bv) { bv = b.x; lab = c + 2; }
        if (b.y > bv) { bv = b.y; lab = c + 3; }
        *(float4*)(o0 + c) = make_float4(a.x, a.y, b.x, b.y);
    }

    // bbox pair: floats 80..89 -> float2 slots 40..44
    float2 q0 = p2[40], q1 = p2[41], q2 = p2[42], q3 = p2[43], q4 = p2[44];
    float b0, b1, b2, b3, b4;
    if (q4.y > q2.x) { b0 = q2.y; b1 = q3.x; b2 = q3.y; b3 = q4.x; b4 = q4.y; }
    else             { b0 = q0.x; b1 = q0.y; b2 = q1.x; b3 = q1.y; b4 = q2.x; }

    float* o1 = out1 + (size_t)cell * 5;
    o1[0] = b0; o1[1] = b1; o1[2] = b2; o1[3] = b3; o1[4] = b4;

    int g = cell & (G2 - 1);
    float xg = (float)(g & (G - 1));
    float yg = (float)(g >> 5);
    // match reference op order exactly (no contraction; /32 and /2 exact)
    float cx = (b0 + xg) / 32.0f;
    float cy = (b1 + yg) / 32.0f;
    float hw = b2 / 2.0f, hh = b3 / 2.0f;
    float x0 = (cx - hw) * IMGW;
    float y0 = (cy - hh) * IMGW;
    float x1 = (cx + hw) * IMGW;
    float y1 = (cy + hh) * IMGW;
    x0 = fminf(fmaxf(x0, 0.0f), IMGW);
    y0 = fminf(fmaxf(y0, 0.0f), IMGW);
    x1 = fminf(fmaxf(x1, 0.0f), IMGW);
    y1 = fminf(fmaxf(y1, 0.0f), IMGW);

    float4 bx = make_float4(x0, y0, x1, y1);
    *(float4*)(out2 + (size_t)cell * 4) = bx;
    out3[cell] = b4;
    out4[cell] = (b4 > 0.1f) ? 1.0f : 0.0f;

    ws_boxes[cell] = bx;
    ws_score[cell] = b4;
    ws_label[cell] = lab;
}

// ---------------------------------------------------------------------------
// Kernel 2: per-image NMS. One 1024-thread block per image.
// Greedy NMS on obox (class-offset boxes) decomposes exactly into
// independent per-class NMS because cross-class IoU is exactly 0.
// Sort key = (class | score-descending | index-ascending)  == stable
// argsort(-eff) restricted per class. Non-reserved cells -> sentinel class
// 127 (they never suppress nor get kept).
// ---------------------------------------------------------------------------
__global__ __launch_bounds__(1024) void nms_kernel(
    const float4* __restrict__ ws_boxes, const float* __restrict__ ws_score,
    const int* __restrict__ ws_label, float* __restrict__ out5)
{
#pragma clang fp contract(off)
    __shared__ unsigned long long key[G2];
    __shared__ float4 obox[G2];
    __shared__ float area_s[G2];
    __shared__ unsigned char keep_s[G2];
    __shared__ int cls_start[128];
    __shared__ int cls_end[128];
    __shared__ float red[16];

    const int n = blockIdx.x;
    const int t = threadIdx.x;
    const int cell = n * G2 + t;

    float4 b = ws_boxes[cell];
    float sc = ws_score[cell];
    int lab = ws_label[cell];
    bool res = sc > 0.1f;

    // ---- max_coord = max over reserved cells of clipped coords (>=0) ----
    float m = res ? fmaxf(fmaxf(b.x, b.y), fmaxf(b.z, b.w)) : 0.0f;
#pragma unroll
    for (int o = 32; o > 0; o >>= 1) m = fmaxf(m, __shfl_xor(m, o, 64));
    if ((t & 63) == 0) red[t >> 6] = m;
    __syncthreads();
    if (t == 0) {
        float mm = red[0];
#pragma unroll
        for (int i = 1; i < 16; ++i) mm = fmaxf(mm, red[i]);
        red[0] = mm;
    }
    __syncthreads();
    float mult = red[0] + 1.0f;

    // ---- obox + sort key ----
    float off = (float)lab * mult;   // one rounding, matches numpy (no fma)
    obox[t] = make_float4(b.x + off, b.y + off, b.z + off, b.w + off);
    float eff = res ? sc : -1.0f;
    unsigned u = __float_as_uint(eff);
    u = (u >> 31) ? ~u : (u | 0x80000000u);   // order-preserving map
    unsigned d = ~u;                          // descending
    int slab = res ? lab : 127;
    key[t] = ((unsigned long long)slab << 42) |
             ((unsigned long long)d << 10) | (unsigned)t;
    if (t < 128) { cls_start[t] = 0; cls_end[t] = 0; }
    __syncthreads();

    // ---- bitonic sort (1024 keys, unique due to idx bits) ----
    for (int k = 2; k <= G2; k <<= 1) {
        for (int j = k >> 1; j > 0; j >>= 1) {
            int ixj = t ^ j;
            if (ixj > t) {
                unsigned long long a = key[t], c = key[ixj];
                bool up = ((t & k) == 0);
                if ((a > c) == up) { key[t] = c; key[ixj] = a; }
            }
            __syncthreads();
        }
    }

    // ---- gather sorted oboxes, class segment boundaries ----
    int p = (int)(key[t] & 1023u);
    int slab_t = (int)(key[t] >> 42);
    float4 ob = obox[p];
    int slab_prev = (t > 0) ? (int)(key[t - 1] >> 42) : -1;
    int slab_next = (t < G2 - 1) ? (int)(key[t + 1] >> 42) : -1;
    __syncthreads();   // all obox[p] reads done; cls arrays initialized
    obox[t] = ob;
    area_s[t] = fmaxf(ob.z - ob.x, 0.0f) * fmaxf(ob.w - ob.y, 0.0f);
    keep_s[t] = (slab_t != 127) ? 1 : 0;
    if (slab_t != slab_prev) cls_start[slab_t] = t;
    if (slab_t != slab_next) cls_end[slab_t] = t + 1;
    __syncthreads();

    // ---- per-class serial greedy NMS (thread c owns class c) ----
    if (t < NC) {
        int s = cls_start[t], e = cls_end[t];
        for (int i = s; i < e; ++i) {
            if (!keep_s[i]) continue;
            float4 A = obox[i];
            float aA = area_s[i];
            for (int j = i + 1; j < e; ++j) {
                if (!keep_s[j]) continue;
                float4 B = obox[j];
                float ltx = fmaxf(A.x, B.x);
                float lty = fmaxf(A.y, B.y);
                float rbx = fminf(A.z, B.z);
                float rby = fminf(A.w, B.w);
                float w = fmaxf(rbx - ltx, 0.0f);
                float h = fmaxf(rby - lty, 0.0f);
                float inter = w * h;
                float uni = (aA + area_s[j]) - inter;
                float iou = inter / fmaxf(uni, 1e-9f);  // exact IEEE div
                if (iou > 0.5f) keep_s[j] = 0;
            }
        }
    }
    __syncthreads();

    out5[n * G2 + p] = keep_s[t] ? 1.0f : 0.0f;
}

extern "C" void kernel_launch(void* const* d_in, const int* in_sizes, int n_in,
                              void* d_out, int out_size, void* d_ws, size_t ws_size,
                              hipStream_t stream) {
    const float* x = (const float*)d_in[0];
    float* out = (float*)d_out;
    float* out0 = out;                                    // logits  128*1024*80
    float* out1 = out0 + (size_t)NCELL * NC;              // bboxes  128*1024*5
    float* out2 = out1 + (size_t)NCELL * 5;               // boxes   128*1024*4
    float* out3 = out2 + (size_t)NCELL * 4;               // scores  128*1024
    float* out4 = out3 + (size_t)NCELL;                   // reserve 128*1024
    float* out5 = out4 + (size_t)NCELL;                   // keep    128*1024

    float4* ws_boxes = (float4*)d_ws;                             // 2 MiB
    float*  ws_score = (float*)((char*)d_ws + (size_t)NCELL * 16); // 0.5 MiB
    int*    ws_label = (int*)((char*)d_ws + (size_t)NCELL * 20);   // 0.5 MiB

    percell_kernel<<<NCELL / 256, 256, 0, stream>>>(
        x, out0, out1, out2, out3, out4, ws_boxes, ws_score, ws_label);
    nms_kernel<<<NB, G2, 0, stream>>>(ws_boxes, ws_score, ws_label, out5);
}